// Round 5
// baseline (966.490 us; speedup 1.0000x reference)
//
#include <hip/hip_runtime.h>

// x: (64, 256, 56, 56) f32. Per (b,c): mag = sum(x^2). Per batch: keep channel
// iff count(mags in batch >= own mag) <= 127  (== mag > 128th-largest, tie-exact).
//
// Single fused kernel: 1024 co-resident blocks (4/CU; __launch_bounds__(256,4)
// caps VGPR<=128, LDS ~40B -> residency guaranteed by capacity). 8 rounds x
// 2 planes/block: hold plane in registers across a per-batch atomic barrier
// (128 blocks/batch), so x is read from HBM exactly once. y stores nontemporal.

#define B 64
#define C 256
#define PLANE 3136       // 56*56
#define PLANE4 784       // 3136/4
#define KCH 128          // NUM_CHANNELS
#define NBLK 1024
#define PPR 2048         // planes per round (= 2*NBLK)
#define ROUNDS 8         // 16384 / PPR
#define BPB 128          // blocks per batch (barrier arrival target)

typedef float f32x4 __attribute__((ext_vector_type(4)));

__device__ __forceinline__ float sumsq(f32x4 v) {
    float s = v.x * v.x;
    s = fmaf(v.y, v.y, s);
    s = fmaf(v.z, v.z, s);
    s = fmaf(v.w, v.w, s);
    return s;
}

__global__ __launch_bounds__(256, 4) void fused_kernel(
        const float* __restrict__ x, float* __restrict__ y,
        float* __restrict__ mag, int* __restrict__ cnt) {
    const int tid  = threadIdx.x;
    const int lane = tid & 63;
    const int wid  = tid >> 6;
    __shared__ float ws[2][4];
    __shared__ int flags;

    for (int r = 0; r < ROUNDS; ++r) {
        const int p0   = r * PPR + 2 * blockIdx.x;   // this block's 2 planes
        const int bat  = p0 >> 8;                    // batch index (same for both)
        const int base = bat << 8;

        const f32x4* __restrict__ xp0 =
            reinterpret_cast<const f32x4*>(x + (size_t)p0 * PLANE);
        const f32x4* __restrict__ xp1 = xp0 + PLANE4;

        // ---- load both planes into registers (784 = 3*256 + 16) ----
        f32x4 a0 = xp0[tid], a1 = xp0[tid + 256], a2 = xp0[tid + 512];
        f32x4 b0 = xp1[tid], b1 = xp1[tid + 256], b2 = xp1[tid + 512];
        f32x4 a3 = {0.f, 0.f, 0.f, 0.f}, b3 = {0.f, 0.f, 0.f, 0.f};
        if (tid < 16) { a3 = xp0[tid + 768]; b3 = xp1[tid + 768]; }

        // ---- per-plane sum of squares ----
        float s0 = sumsq(a0) + sumsq(a1) + sumsq(a2) + sumsq(a3);
        float s1 = sumsq(b0) + sumsq(b1) + sumsq(b2) + sumsq(b3);
        for (int off = 32; off > 0; off >>= 1) {
            s0 += __shfl_down(s0, off, 64);
            s1 += __shfl_down(s1, off, 64);
        }
        if (lane == 0) { ws[0][wid] = s0; ws[1][wid] = s1; }
        __syncthreads();

        // ---- publish mags, arrive at per-batch barrier, spin ----
        if (tid == 0) {
            mag[p0]     = (ws[0][0] + ws[0][1]) + (ws[0][2] + ws[0][3]);
            mag[p0 + 1] = (ws[1][0] + ws[1][1]) + (ws[1][2] + ws[1][3]);
            __threadfence();                 // release mags
            atomicAdd(&cnt[bat], 1);
            while (__hip_atomic_load(&cnt[bat], __ATOMIC_RELAXED,
                                     __HIP_MEMORY_SCOPE_AGENT) < BPB) {
                __builtin_amdgcn_s_sleep(1);
            }
        }
        // wave 0 converges here once lane 0 exits the spin
        if (wid == 0) {
            __threadfence();                 // acquire: other blocks' mags fresh
            const float m0 = mag[p0];
            const float m1 = mag[p0 + 1];
            int c0 = 0, c1 = 0;
            for (int k = 0; k < 4; ++k) {
                const float mv = mag[base + k * 64 + lane];
                c0 += __popcll(__ballot(mv >= m0));
                c1 += __popcll(__ballot(mv >= m1));
            }
            if (lane == 0) {
                flags = (c0 <= KCH - 1 ? 1 : 0) | (c1 <= KCH - 1 ? 2 : 0);
            }
        }
        __syncthreads();
        const int fl = flags;

        // ---- write phase: registers -> y (nontemporal), or zeros ----
        f32x4* __restrict__ yp0 = reinterpret_cast<f32x4*>(y + (size_t)p0 * PLANE);
        f32x4* __restrict__ yp1 = yp0 + PLANE4;
        const f32x4 z = {0.f, 0.f, 0.f, 0.f};
        if (fl & 1) {
            __builtin_nontemporal_store(a0, yp0 + tid);
            __builtin_nontemporal_store(a1, yp0 + tid + 256);
            __builtin_nontemporal_store(a2, yp0 + tid + 512);
            if (tid < 16) __builtin_nontemporal_store(a3, yp0 + tid + 768);
        } else {
            __builtin_nontemporal_store(z, yp0 + tid);
            __builtin_nontemporal_store(z, yp0 + tid + 256);
            __builtin_nontemporal_store(z, yp0 + tid + 512);
            if (tid < 16) __builtin_nontemporal_store(z, yp0 + tid + 768);
        }
        if (fl & 2) {
            __builtin_nontemporal_store(b0, yp1 + tid);
            __builtin_nontemporal_store(b1, yp1 + tid + 256);
            __builtin_nontemporal_store(b2, yp1 + tid + 512);
            if (tid < 16) __builtin_nontemporal_store(b3, yp1 + tid + 768);
        } else {
            __builtin_nontemporal_store(z, yp1 + tid);
            __builtin_nontemporal_store(z, yp1 + tid + 256);
            __builtin_nontemporal_store(z, yp1 + tid + 512);
            if (tid < 16) __builtin_nontemporal_store(z, yp1 + tid + 768);
        }
        __syncthreads();   // protect ws/flags before next round overwrites
    }
}

extern "C" void kernel_launch(void* const* d_in, const int* in_sizes, int n_in,
                              void* d_out, int out_size, void* d_ws, size_t ws_size,
                              hipStream_t stream) {
    const float* x = (const float*)d_in[0];
    float* y = (float*)d_out;
    float* mag = (float*)d_ws;            // B*C floats = 64 KB
    int*   cnt = (int*)(mag + B * C);     // 64 ints

    hipMemsetAsync(cnt, 0, B * sizeof(int), stream);  // fresh barrier counters
    fused_kernel<<<NBLK, 256, 0, stream>>>(x, y, mag, cnt);
}

// Round 6
// 567.664 us; speedup vs baseline: 1.7026x; 1.7026x over previous
//
#include <hip/hip_runtime.h>

// x: (64, 256, 56, 56) f32. Per (b,c): mag = sum(x^2). Per batch: keep channel
// iff count(mags in batch >= own mag) <= 127  (== mag > 128th-largest, tie-exact).
//
// Fused single-pass: 1024 co-resident blocks (4/CU by capacity), 8 rounds x
// 2 planes/block. Plane data PINNED in VGPRs across a per-batch arrival
// barrier (asm "+v" identity keeps loads above the spin; compiler cannot
// re-load). All cross-block traffic (mag, cnt) uses relaxed AGENT-scope
// atomics (coherent-point ops, no L2 writeback/invalidate storms); ordering
// mag-stores -> cnt-add via explicit s_waitcnt vmcnt(0).

#define B 64
#define C 256
#define PLANE 3136       // 56*56
#define PLANE4 784       // 3136/4
#define KCH 128          // NUM_CHANNELS
#define NBLK 1024
#define PPR 2048         // planes per round (= 2*NBLK)
#define ROUNDS 8         // 16384 / PPR
#define BPB 128          // blocks per batch (barrier arrival target)

typedef float f32x4 __attribute__((ext_vector_type(4)));

__device__ __forceinline__ float sumsq(f32x4 v) {
    float s = v.x * v.x;
    s = fmaf(v.y, v.y, s);
    s = fmaf(v.z, v.z, s);
    s = fmaf(v.w, v.w, s);
    return s;
}

__global__ __launch_bounds__(256, 4) void fused_kernel(
        const float* __restrict__ x, float* __restrict__ y,
        float* __restrict__ mag, int* __restrict__ cnt) {
    const int tid  = threadIdx.x;
    const int lane = tid & 63;
    const int wid  = tid >> 6;
    __shared__ float ws[2][4];
    __shared__ int flags;

    for (int r = 0; r < ROUNDS; ++r) {
        const int p0   = r * PPR + 2 * blockIdx.x;   // this block's 2 planes
        const int bat  = p0 >> 8;                    // batch index (same for both)
        const int base = bat << 8;

        const f32x4* __restrict__ xp0 =
            reinterpret_cast<const f32x4*>(x + (size_t)p0 * PLANE);
        const f32x4* __restrict__ xp1 = xp0 + PLANE4;

        // ---- load both planes into registers (784 = 3*256 + 16) ----
        f32x4 a0 = xp0[tid], a1 = xp0[tid + 256], a2 = xp0[tid + 512];
        f32x4 b0 = xp1[tid], b1 = xp1[tid + 256], b2 = xp1[tid + 512];
        f32x4 a3 = {0.f, 0.f, 0.f, 0.f}, b3 = {0.f, 0.f, 0.f, 0.f};
        if (tid < 16) { a3 = xp0[tid + 768]; b3 = xp1[tid + 768]; }

        // ---- per-plane sum of squares ----
        float s0 = sumsq(a0) + sumsq(a1) + sumsq(a2) + sumsq(a3);
        float s1 = sumsq(b0) + sumsq(b1) + sumsq(b2) + sumsq(b3);

        // PIN plane data in VGPRs: post-barrier stores consume these asm
        // outputs, so the compiler cannot sink the loads below the barrier.
        asm volatile("" : "+v"(a0), "+v"(a1), "+v"(a2), "+v"(a3),
                         "+v"(b0), "+v"(b1), "+v"(b2), "+v"(b3));

        for (int off = 32; off > 0; off >>= 1) {
            s0 += __shfl_down(s0, off, 64);
            s1 += __shfl_down(s1, off, 64);
        }
        if (lane == 0) { ws[0][wid] = s0; ws[1][wid] = s1; }
        __syncthreads();

        // ---- publish mags (coherent-point), arrive, spin ----
        if (tid == 0) {
            const float m0 = (ws[0][0] + ws[0][1]) + (ws[0][2] + ws[0][3]);
            const float m1 = (ws[1][0] + ws[1][1]) + (ws[1][2] + ws[1][3]);
            __hip_atomic_store(&mag[p0], m0, __ATOMIC_RELAXED,
                               __HIP_MEMORY_SCOPE_AGENT);
            __hip_atomic_store(&mag[p0 + 1], m1, __ATOMIC_RELAXED,
                               __HIP_MEMORY_SCOPE_AGENT);
            asm volatile("s_waitcnt vmcnt(0)" ::: "memory");  // mags durable first
            __hip_atomic_fetch_add(&cnt[bat], 1, __ATOMIC_RELAXED,
                                   __HIP_MEMORY_SCOPE_AGENT);
            while (__hip_atomic_load(&cnt[bat], __ATOMIC_RELAXED,
                                     __HIP_MEMORY_SCOPE_AGENT) < BPB) {
                __builtin_amdgcn_s_sleep(8);
            }
        }
        // wave 0 reconverges after lane 0 exits the spin
        if (wid == 0) {
            const float m0 = __hip_atomic_load(&mag[p0], __ATOMIC_RELAXED,
                                               __HIP_MEMORY_SCOPE_AGENT);
            const float m1 = __hip_atomic_load(&mag[p0 + 1], __ATOMIC_RELAXED,
                                               __HIP_MEMORY_SCOPE_AGENT);
            int c0 = 0, c1 = 0;
            for (int k = 0; k < 4; ++k) {
                const float mv = __hip_atomic_load(&mag[base + k * 64 + lane],
                                                   __ATOMIC_RELAXED,
                                                   __HIP_MEMORY_SCOPE_AGENT);
                c0 += __popcll(__ballot(mv >= m0));
                c1 += __popcll(__ballot(mv >= m1));
            }
            if (lane == 0) {
                flags = (c0 <= KCH - 1 ? 1 : 0) | (c1 <= KCH - 1 ? 2 : 0);
            }
        }
        __syncthreads();
        const int fl = flags;

        // ---- write phase: pinned registers -> y (nontemporal), or zeros ----
        f32x4* __restrict__ yp0 = reinterpret_cast<f32x4*>(y + (size_t)p0 * PLANE);
        f32x4* __restrict__ yp1 = yp0 + PLANE4;
        const f32x4 z = {0.f, 0.f, 0.f, 0.f};
        if (fl & 1) {
            __builtin_nontemporal_store(a0, yp0 + tid);
            __builtin_nontemporal_store(a1, yp0 + tid + 256);
            __builtin_nontemporal_store(a2, yp0 + tid + 512);
            if (tid < 16) __builtin_nontemporal_store(a3, yp0 + tid + 768);
        } else {
            __builtin_nontemporal_store(z, yp0 + tid);
            __builtin_nontemporal_store(z, yp0 + tid + 256);
            __builtin_nontemporal_store(z, yp0 + tid + 512);
            if (tid < 16) __builtin_nontemporal_store(z, yp0 + tid + 768);
        }
        if (fl & 2) {
            __builtin_nontemporal_store(b0, yp1 + tid);
            __builtin_nontemporal_store(b1, yp1 + tid + 256);
            __builtin_nontemporal_store(b2, yp1 + tid + 512);
            if (tid < 16) __builtin_nontemporal_store(b3, yp1 + tid + 768);
        } else {
            __builtin_nontemporal_store(z, yp1 + tid);
            __builtin_nontemporal_store(z, yp1 + tid + 256);
            __builtin_nontemporal_store(z, yp1 + tid + 512);
            if (tid < 16) __builtin_nontemporal_store(z, yp1 + tid + 768);
        }
        __syncthreads();   // protect ws/flags before next round overwrites
    }
}

extern "C" void kernel_launch(void* const* d_in, const int* in_sizes, int n_in,
                              void* d_out, int out_size, void* d_ws, size_t ws_size,
                              hipStream_t stream) {
    const float* x = (const float*)d_in[0];
    float* y = (float*)d_out;
    float* mag = (float*)d_ws;            // B*C floats = 64 KB
    int*   cnt = (int*)(mag + B * C);     // 64 ints

    hipMemsetAsync(cnt, 0, B * sizeof(int), stream);  // fresh barrier counters
    fused_kernel<<<NBLK, 256, 0, stream>>>(x, y, mag, cnt);
}